// Round 15
// baseline (273.304 us; speedup 1.0000x reference)
//
#include <hip/hip_runtime.h>
#include <math.h>

// ---------------- problem constants ----------------
#define BATCH   256
#define NCLS    10
#define DIM     48

// ---------------- workspace layout (float elements) ----------------
// d_ws is 268 MB (67.1M floats) — everything now DISJOINT, zero aliasing.
#define OFF_PAIR  0            // 589824
#define OFF_FC1P  602112       // ends 2699264
#define OFF_PTFH  4500000      // 144*18*64*8 u16 = 663552 fl -> ends 5163552
#define OFF_PTFL  5300000      // ends 5963552
#define OFF_POOL  7372800      // ends 10584064
#define OFF_DO    10596352
#define OFF_CW    10608640
#define OFF_INT   10608656     // ints: cls_cnt[16], cls_idx[2560] -> ends 10611232
#define OFF_WT    11000000     // 12544*128 -> ends 12605632

typedef __attribute__((ext_vector_type(8))) short short8;
typedef __attribute__((ext_vector_type(4))) float floatx4;
typedef unsigned short u16;
typedef unsigned int u32;

__device__ __forceinline__ u16 f2bf(float v) {
    u32 u = __float_as_uint(v);
    return (u16)((u + 0x7fffu + ((u >> 16) & 1u)) >> 16);
}
__device__ __forceinline__ float bf2f(u16 h) {
    return __uint_as_float(((u32)h) << 16);
}

__device__ __forceinline__ float sroot_half(float m) {
    float s = (m < 0.f) ? -1.f : 1.f;
    return s * (sqrtf(fabsf(m) + 0.25f) - 0.5f);
}
__device__ __forceinline__ float sroot_cbrt(float m) {
    float s = (m < 0.f) ? -1.f : 1.f;
    return s * (cbrtf(fabsf(m) + 0.19245008973f) - 0.57735026919f);
}
__device__ __forceinline__ float sroot_quarter(float m) {
    float s = (m < 0.f) ? -1.f : 1.f;
    return s * (sqrtf(sqrtf(fabsf(m) + 0.15749013123f)) - 0.62996052494f);
}

// ======= fused conv1(LDS)+conv2+pool via MFMA, + folded wtrans + init =======
// blocks [0,1024) = (b, 2x2 quadrant). blocks [1024,2592): fc1-W transpose.
// Phase order: stage x -> conv1 -> sched_barrier -> load B-frags -> MFMA.
// hs row stride 88 u16 (176 B, 16B-aligned, ~2-way banks).
__global__ void k_conv12(const float* __restrict__ x, const float* __restrict__ c1w,
                         const float* __restrict__ c1b, const float* __restrict__ c2w,
                         const float* __restrict__ c2b, float* __restrict__ pooled,
                         const float* __restrict__ f1w, float* __restrict__ wT,
                         float* __restrict__ cw, int* __restrict__ cls_cnt,
                         float* __restrict__ out) {
    __shared__ __align__(16) u16 hs[256 * 88];   // 45 KB
    __shared__ __align__(16) float xs[972];      // 3.9 KB: [ic(3)][18][18]
    int blk = blockIdx.x;
    int tid = threadIdx.x;
    if (blk >= 1024) {
        // ---- fc1-W transpose: wT[k][n] = f1w[n][k], 32x32 tiles ----
        float* tile = (float*)hs;                // 32 x 33
        int wb = blk - 1024;
        int kb = wb % 392, nb = wb / 392;
        int tx = tid & 31, ty = tid >> 5;
        int k0 = kb * 32, n0 = nb * 32;
#pragma unroll
        for (int r = 0; r < 4; r++)
            tile[tx * 33 + ty * 4 + r] = f1w[(n0 + ty * 4 + r) * 12544 + k0 + tx];
        __syncthreads();
#pragma unroll
        for (int r = 0; r < 4; r++)
            wT[(k0 + ty * 4 + r) * 128 + n0 + tx] = tile[(ty * 4 + r) * 33 + tx];
        return;
    }
    if (blk == 0) {
        if (tid < 16) { cw[tid] = 0.f; cls_cnt[tid] = 0; }
        else if (tid < 20) out[2560 + tid - 16] = 0.f;
    }
    int b = blk >> 2, sub = blk & 3;
    int hy = sub >> 1, hx = sub & 1;
    int row0 = hy * 14, col0 = hx * 14;
    // stage x window [row0..row0+17][col0..col0+17] x 3 ic
    for (int i = tid; i < 972; i += 256) {
        int ic = i / 324, r2 = i % 324;
        int rr = r2 / 18, cc = r2 % 18;
        xs[i] = x[b * 3072 + ic * 1024 + (row0 + rr) * 32 + col0 + cc];
    }
    __syncthreads();
    // conv1 for local position tid (16x16 window) -> hs[tid*88 ...]
    {
        int r = tid >> 4, c = tid & 15;
        float win[27];
#pragma unroll
        for (int ic = 0; ic < 3; ic++)
#pragma unroll
            for (int ky = 0; ky < 3; ky++)
#pragma unroll
                for (int kx = 0; kx < 3; kx++)
                    win[ic * 9 + ky * 3 + kx] = xs[ic * 324 + (r + ky) * 18 + c + kx];
        u16* hp = hs + tid * 88;
#pragma unroll
        for (int ch = 0; ch < 4; ch++) {
            u32 hiw[4], low[4];
#pragma unroll
            for (int a2 = 0; a2 < 4; a2++) {
                u16 h2[2], l2[2];
#pragma unroll
                for (int e = 0; e < 2; e++) {
                    int oc = ch * 8 + a2 * 2 + e;
                    float s = c1b[oc];
#pragma unroll
                    for (int k = 0; k < 27; k++) s = fmaf(win[k], c1w[oc * 27 + k], s);
                    s = fmaxf(s, 0.f);
                    u16 hi = f2bf(s);
                    h2[e] = hi;
                    l2[e] = f2bf(s - bf2f(hi));
                }
                hiw[a2] = (u32)h2[0] | ((u32)h2[1] << 16);
                low[a2] = (u32)l2[0] | ((u32)l2[1] << 16);
            }
            *(uint4*)(hp + ch * 8)      = make_uint4(hiw[0], hiw[1], hiw[2], hiw[3]);
            *(uint4*)(hp + 32 + ch * 8) = make_uint4(low[0], low[1], low[2], low[3]);
        }
    }
    __builtin_amdgcn_sched_barrier(0);     // keep B-frag loads AFTER conv1 (no spill)
    __syncthreads();                       // hs ready
    // B fragments per lane from c2w
    int wv = tid >> 6, lane = tid & 63;
    int n = lane & 15, quad = lane >> 4;
    int ocb = wv * 16 + n;
    float bv = c2b[ocb];
    short8 bh[9], bl[9];
#pragma unroll
    for (int s = 0; s < 9; s++) {
        short8 hv, lv;
#pragma unroll
        for (int j = 0; j < 8; j++) {
            float v = c2w[(ocb * 32 + quad * 8 + j) * 9 + s];
            u16 hi = f2bf(v);
            hv[j] = (short)hi;
            lv[j] = (short)f2bf(v - bf2f(hi));
        }
        bh[s] = hv; bl[s] = lv;
    }
    int ml = lane & 15;
    for (int t = 0; t < 13; t++) {
        int gA = t * 4 + (ml >> 2);
        int d = ml & 3;
        int gc = (gA < 49) ? gA : 0;
        int py = gc / 7, px = gc % 7;
        int rb = 2 * py + (d >> 1), cb = 2 * px + (d & 1);
        floatx4 acc = {0.f, 0.f, 0.f, 0.f};
#pragma unroll
        for (int s = 0; s < 9; s++) {
            int ky = s / 3, kx = s % 3;
            int pos = (rb + ky) * 16 + cb + kx;
            short8 ah = *(const short8*)(&hs[pos * 88 + quad * 8]);
            short8 al = *(const short8*)(&hs[pos * 88 + 32 + quad * 8]);
            acc = __builtin_amdgcn_mfma_f32_16x16x32_bf16(ah, bh[s], acc, 0, 0, 0);
            acc = __builtin_amdgcn_mfma_f32_16x16x32_bf16(ah, bl[s], acc, 0, 0, 0);
            acc = __builtin_amdgcn_mfma_f32_16x16x32_bf16(al, bh[s], acc, 0, 0, 0);
        }
        int G = t * 4 + quad;
        if (G < 49) {
            float v = fmaxf(fmaxf(acc.x, acc.y), fmaxf(acc.z, acc.w));
            v = fmaxf(v + bv, 0.f);
            int pyg = hy * 7 + G / 7, pxg = hx * 7 + G % 7;
            pooled[(size_t)b * 12544 + ocb * 196 + pyg * 14 + pxg] = v;
        }
    }
}

// ---------------- fc1 K-split GEMM ----------------
__global__ void k_fc1(const float* __restrict__ pooled, const float* __restrict__ wT,
                      float* __restrict__ fc1p) {
    __shared__ __align__(16) float Alds[16 * 196];
    int blk = blockIdx.x;
    int sg = blk >> 6, kc = blk & 63;
    int tid = threadIdx.x;
    int m0 = sg * 16, k0 = kc * 196;
    for (int i = tid; i < 784; i += 256) {
        int m = i / 49, u = i % 49;
        ((float4*)Alds)[m * 49 + u] = ((const float4*)(pooled + (m0 + m) * 12544 + k0))[u];
    }
    __syncthreads();
    int n2 = tid & 63, mg = tid >> 6;
    const float* wp = wT + (size_t)k0 * 128 + n2;
    const float* arow = Alds + mg * 4 * 196;
    float acc[4][2];
#pragma unroll
    for (int j = 0; j < 4; j++) { acc[j][0] = 0.f; acc[j][1] = 0.f; }
    for (int k = 0; k < 196; k += 2) {
        float wa0 = wp[k * 128],        wb0 = wp[k * 128 + 64];
        float wa1 = wp[(k + 1) * 128],  wb1 = wp[(k + 1) * 128 + 64];
#pragma unroll
        for (int j = 0; j < 4; j++) {
            float2 av = *(const float2*)(arow + j * 196 + k);
            acc[j][0] = fmaf(av.x, wa0, acc[j][0]);
            acc[j][0] = fmaf(av.y, wa1, acc[j][0]);
            acc[j][1] = fmaf(av.x, wb0, acc[j][1]);
            acc[j][1] = fmaf(av.y, wb1, acc[j][1]);
        }
    }
#pragma unroll
    for (int j = 0; j < 4; j++) {
        int m = m0 + mg * 4 + j;
        fc1p[kc * 32768 + m * 128 + n2]      = acc[j][0];
        fc1p[kc * 32768 + m * 128 + n2 + 64] = acc[j][1];
    }
}

// ------- fc1-reduce + fc2 + fc3 + assignment + pair row -------
__global__ void k_fc23a(const float* __restrict__ fc1p, const float* __restrict__ f1b,
                        const float* __restrict__ w2, const float* __restrict__ b2,
                        const float* __restrict__ w3, const float* __restrict__ b3,
                        const float* __restrict__ centers, float* __restrict__ out,
                        float* __restrict__ dov, float* __restrict__ pairm,
                        float* __restrict__ cw, int* __restrict__ cls_cnt,
                        int* __restrict__ cls_idx) {
    __shared__ float a[128], h[128], zb[48], dvs[48];
    __shared__ float dist[10];
    __shared__ float smn, ssum;
    __shared__ int sarg;
    int b = blockIdx.x, t = threadIdx.x;
    float s0 = f1b[t];
    for (int p = 0; p < 64; p++) s0 += fc1p[p * 32768 + b * 128 + t];
    a[t] = fmaxf(s0, 0.f);
    __syncthreads();
    float s = b2[t];
    const float* wr = w2 + t * 128;
#pragma unroll 4
    for (int k = 0; k < 128; k++) s = fmaf(wr[k], a[k], s);
    h[t] = fmaxf(s, 0.f);
    __syncthreads();
    if (t < 48) {
        float s3 = b3[t];
        const float* wr3 = w3 + t * 128;
#pragma unroll 4
        for (int k = 0; k < 128; k++) s3 = fmaf(wr3[k], h[k], s3);
        zb[t] = s3;
    }
    __syncthreads();
    if (t < 10) {
        float d = 0.f;
        const float* cc = centers + t * 48;
        for (int k = 0; k < 48; k++) { float df = zb[k] - cc[k]; d = fmaf(df, df, d); }
        dist[t] = d;
    }
    __syncthreads();
    if (t == 0) {
        float mn = dist[0]; int arg = 0;
        for (int c = 1; c < 10; c++) if (dist[c] < mn) { mn = dist[c]; arg = c; }
        float sum = 0.f;
        for (int c = 0; c < 10; c++) sum += expf(-0.5f * (dist[c] - mn));
        smn = mn; ssum = sum; sarg = arg;
        atomicAdd(&cw[arg], 1.f);
        int pos = atomicAdd(&cls_cnt[arg], 1);
        cls_idx[arg * 256 + pos] = b;
    }
    __syncthreads();
    if (t < 10) {
        float es = -0.5f * (dist[t] - smn);
        float resp = expf(es) / ssum;
        out[b * 10 + t] = logf(fmaxf(resp, 1e-8f));
    }
    if (t < 48) {
        float v = zb[t] - centers[sarg * 48 + t];
        dvs[t] = v;
        dov[b * 48 + t] = v;
    }
    __syncthreads();
#pragma unroll
    for (int e = 0; e < 18; e++) {
        int cell = t + 128 * e;
        pairm[b * 2304 + cell] = dvs[cell / 48] * dvs[cell % 48];
    }
}

// ------- prep: ptrans->fragment order (648) + p3 (360) + m12 split (90) -------
__global__ void k_prep(const float* __restrict__ pairm, const float* __restrict__ dov,
                       const float* __restrict__ cw, const int* __restrict__ cls_cnt,
                       const int* __restrict__ cls_idx, const float* __restrict__ momw,
                       const float* __restrict__ gm1, const float* __restrict__ gm2,
                       const float* __restrict__ gm3, u16* __restrict__ ptfh,
                       u16* __restrict__ ptfl, float* __restrict__ out) {
    __shared__ __align__(16) float smem[7424];       // 29.7 KB
    int blk = blockIdx.x;
    int t = threadIdx.x;

    if (blk < 648) {
        float* tile = smem;               // 32 cols x 64 cells, stride 65
        int* cmap = (int*)(smem + 2080);
        int ctile = blk / 18, coltile = blk % 18;
        int cell0 = ctile * 64, col0 = coltile * 32;
        if (t < 32) {
            int j = col0 + t, base = 0, samp = -1;
            for (int c = 0; c < 10; c++) {
                int cnt = cls_cnt[c];
                if (j >= base && j < base + cnt) samp = cls_idx[c * 256 + (j - base)];
                base += (cnt + 31) & ~31;
            }
            cmap[t] = samp;
        }
        __syncthreads();
        for (int i = t; i < 2048; i += 256) {
            int u = i >> 6, ce = i & 63;
            int s = cmap[u];
            tile[u * 65 + ce] = (s >= 0) ? pairm[(size_t)s * 2304 + cell0 + ce] : 0.f;
        }
        __syncthreads();
        int kc = col0 >> 5;
        int rt0 = cell0 >> 4;
        for (int o = t; o < 2048; o += 256) {
            int rtl = o >> 9, lane = (o >> 3) & 63, j = o & 7;
            int m = lane & 15, quad = lane >> 4;
            float v = tile[(quad * 8 + j) * 65 + rtl * 16 + m];
            u16 hi = f2bf(v);
            size_t off = ((size_t)((rt0 + rtl) * 18 + kc) * 64 + lane) * 8 + j;
            ptfh[off] = hi;
            ptfl[off] = f2bf(v - bf2f(hi));
        }

    } else if (blk < 1008) {
        // ---- p3 ----
        float* Pl = smem;
        float* Dl = smem + 4096;
        float* red = smem + 7168;
        int bb = blk - 648;
        int c = bb / 36, pt = bb % 36;
        int cnt = cls_cnt[c];
        const int* cidx = cls_idx + c * 256;
        int pl = t >> 2, kq = t & 3;
        float acc[12];
#pragma unroll
        for (int m = 0; m < 12; m++) acc[m] = 0.f;
        for (int s0 = 0; s0 < cnt; s0 += 64) {
            int sc = min(64, cnt - s0);
            __syncthreads();
            for (int i = t; i < sc * 16; i += 256) {
                int row = i >> 4, u = i & 15;
                ((float4*)Pl)[row * 16 + u] =
                    ((const float4*)(pairm + (size_t)cidx[s0 + row] * 2304 + pt * 64))[u];
            }
            for (int i = t; i < sc * 12; i += 256) {
                int row = i / 12, u = i % 12;
                ((float4*)Dl)[row * 12 + u] =
                    ((const float4*)(dov + (size_t)cidx[s0 + row] * 48))[u];
            }
            __syncthreads();
            for (int s = 0; s < sc; s++) {
                float pa = Pl[s * 64 + pl];
                float4 d0 = *(const float4*)&Dl[s * 48 + kq * 12];
                float4 d1 = *(const float4*)&Dl[s * 48 + kq * 12 + 4];
                float4 d2 = *(const float4*)&Dl[s * 48 + kq * 12 + 8];
                acc[0]  = fmaf(pa, d0.x, acc[0]);  acc[1]  = fmaf(pa, d0.y, acc[1]);
                acc[2]  = fmaf(pa, d0.z, acc[2]);  acc[3]  = fmaf(pa, d0.w, acc[3]);
                acc[4]  = fmaf(pa, d1.x, acc[4]);  acc[5]  = fmaf(pa, d1.y, acc[5]);
                acc[6]  = fmaf(pa, d1.z, acc[6]);  acc[7]  = fmaf(pa, d1.w, acc[7]);
                acc[8]  = fmaf(pa, d2.x, acc[8]);  acc[9]  = fmaf(pa, d2.y, acc[9]);
                acc[10] = fmaf(pa, d2.z, acc[10]); acc[11] = fmaf(pa, d2.w, acc[11]);
            }
        }
        float cwn = cw[c] * (1.f / 256.f);
        int p = pt * 64 + pl;
        float p3c = 0.f;
#pragma unroll
        for (int m = 0; m < 12; m++) {
            int k = kq * 12 + m;
            float d3 = sroot_cbrt(acc[m]) - sroot_cbrt(gm3[p * 48 + k]);
            p3c += momw[k] * d3 * d3;
        }
        p3c *= cwn;
        red[t] = p3c; __syncthreads();
        for (int off = 128; off > 0; off >>= 1) { if (t < off) red[t] += red[t + off]; __syncthreads(); }
        if (t == 0) atomicAdd(&out[2562], red[0]);

    } else {
        // ---- m1/m2 split by r: 10 classes x 9 r-slices ----
        float* ds = smem;
        float* red = smem + 3072;
        int bb = blk - 1008;
        int c = bb / 9, r = bb % 9;
        int cnt = cls_cnt[c];
        const int* cidx = cls_idx + c * 256;
        int cell = t + 256 * r;
        int ci = cell / 48, cj = cell % 48;
        float a0 = 0.f, a1 = 0.f, a2 = 0.f, a3 = 0.f;
        float m1a = 0.f, m1b = 0.f;
        for (int s0 = 0; s0 < cnt; s0 += 64) {
            int sc = min(64, cnt - s0);
            __syncthreads();
            for (int i = t; i < sc * 48; i += 256)
                ds[i] = dov[(size_t)cidx[s0 + i / 48] * 48 + (i % 48)];
            __syncthreads();
            int s = 0;
            for (; s + 4 <= sc; s += 4) {
                a0 = fmaf(ds[s * 48 + ci],       ds[s * 48 + cj],       a0);
                a1 = fmaf(ds[(s + 1) * 48 + ci], ds[(s + 1) * 48 + cj], a1);
                a2 = fmaf(ds[(s + 2) * 48 + ci], ds[(s + 2) * 48 + cj], a2);
                a3 = fmaf(ds[(s + 3) * 48 + ci], ds[(s + 3) * 48 + cj], a3);
            }
            for (; s < sc; s++) a0 = fmaf(ds[s * 48 + ci], ds[s * 48 + cj], a0);
            if (r == 0 && t < 48) {
                int ss = 0;
                for (; ss + 2 <= sc; ss += 2) {
                    m1a += ds[ss * 48 + t];
                    m1b += ds[(ss + 1) * 48 + t];
                }
                for (; ss < sc; ss++) m1a += ds[ss * 48 + t];
            }
        }
        float denom = cw[c] + 1e-7f;
        float cwn = cw[c] * (1.f / 256.f);
        float m2v = (a0 + a1 + a2 + a3) / denom;
        float d2 = sroot_half(m2v) - sroot_half(gm2[cell]);
        float p2c = cwn * momw[cj] * d2 * d2;
        __syncthreads();
        red[t] = p2c; __syncthreads();
        for (int off = 128; off > 0; off >>= 1) { if (t < off) red[t] += red[t + off]; __syncthreads(); }
        if (t == 0) atomicAdd(&out[2561], red[0]);
        if (r == 0 && t < 48) {
            float m1v = (m1a + m1b) / denom;
            float d1 = m1v - gm1[t];
            atomicAdd(&out[2560], cwn * momw[t] * d1 * d1);
        }
    }
}

// ---- p4: M4 = P^T P per class via MFMA on fragment-ordered ptf ----
__global__ __launch_bounds__(256, 4)
void k_p4(const u16* __restrict__ ptfh, const u16* __restrict__ ptfl,
          const float* __restrict__ cw, const int* __restrict__ cls_cnt,
          const float* __restrict__ momw, float* __restrict__ out) {
    __shared__ float red[256];
    int blk = blockIdx.x;
    int c = blk / 171;
    int cnt = cls_cnt[c];
    if (cnt == 0) return;
    int rem = blk % 171;
    int pt = 0;
    while (rem >= 18 - pt) { rem -= 18 - pt; pt++; }
    int qt = pt + rem;
    int kc0 = 0;
    for (int cc = 0; cc < c; cc++) kc0 += (cls_cnt[cc] + 31) >> 5;
    int kch = (cnt + 31) >> 5;
    int t = threadIdx.x;
    int w = t >> 6, lane = t & 63;
    int ml = lane & 15, quad = lane >> 4;
    floatx4 acc[16];
#pragma unroll
    for (int i = 0; i < 16; i++) acc[i] = (floatx4){0.f, 0.f, 0.f, 0.f};
    for (int kc = 0; kc < kch; kc++) {
        short8 ah[2], al[2];
#pragma unroll
        for (int ms = 0; ms < 2; ms++) {
            int art = pt * 8 + w * 2 + ms;
            size_t aoff = ((size_t)(art * 18 + kc0 + kc) * 64 + lane) * 8;
            ah[ms] = *(const short8*)(ptfh + aoff);
            al[ms] = *(const short8*)(ptfl + aoff);
        }
#pragma unroll
        for (int ns = 0; ns < 8; ns++) {
            int brt = qt * 8 + ns;
            size_t boff = ((size_t)(brt * 18 + kc0 + kc) * 64 + lane) * 8;
            short8 bhv = *(const short8*)(ptfh + boff);
            short8 blv = *(const short8*)(ptfl + boff);
#pragma unroll
            for (int ms = 0; ms < 2; ms++) {
                int id = ms * 8 + ns;
                acc[id] = __builtin_amdgcn_mfma_f32_16x16x32_bf16(ah[ms], bhv, acc[id], 0, 0, 0);
                acc[id] = __builtin_amdgcn_mfma_f32_16x16x32_bf16(ah[ms], blv, acc[id], 0, 0, 0);
                acc[id] = __builtin_amdgcn_mfma_f32_16x16x32_bf16(al[ms], bhv, acc[id], 0, 0, 0);
            }
        }
    }
    float T1 = sroot_quarter(1.f), T3 = sroot_quarter(3.f);
    float cwn = cw[c] * (1.f / 256.f);
    bool diag = (pt == qt);
    int ipv[8], jpv[8];
    float mwpv[8];
#pragma unroll
    for (int ms = 0; ms < 2; ms++)
#pragma unroll
        for (int reg = 0; reg < 4; reg++) {
            int p = (pt * 8 + w * 2 + ms) * 16 + quad * 4 + reg;
            ipv[ms * 4 + reg] = p / 48;
            jpv[ms * 4 + reg] = p % 48;
            mwpv[ms * 4 + reg] = momw[p % 48];
        }
    float p4c = 0.f;
#pragma unroll
    for (int ns = 0; ns < 8; ns++) {
        int q = (qt * 8 + ns) * 16 + ml;
        int kq = q / 48, lq = q % 48;
        float mq = momw[lq];
#pragma unroll
        for (int ms = 0; ms < 2; ms++) {
            int id = ms * 8 + ns;
#pragma unroll
            for (int reg = 0; reg < 4; reg++) {
                int ip = ipv[ms * 4 + reg], jp = jpv[ms * 4 + reg];
                int g = ((ip == jp) && (kq == lq))
                      + ((ip == kq) && (jp == lq))
                      + ((ip == lq) && (jp == kq));
                float t4v = (g == 0) ? 0.f : ((g == 1) ? T1 : T3);
                float d4 = sroot_quarter(acc[id][reg]) - t4v;
                float wgt = diag ? mq : (mq + mwpv[ms * 4 + reg]);
                p4c += wgt * d4 * d4;
            }
        }
    }
    p4c *= cwn;
    red[t] = p4c; __syncthreads();
    for (int off = 128; off > 0; off >>= 1) { if (t < off) red[t] += red[t + off]; __syncthreads(); }
    if (t == 0) atomicAdd(&out[2563], red[0]);
}

// ---------------- launch ----------------
extern "C" void kernel_launch(void* const* d_in, const int* in_sizes, int n_in,
                              void* d_out, int out_size, void* d_ws, size_t ws_size,
                              hipStream_t stream) {
    const float* x    = (const float*)d_in[0];
    const float* c1w  = (const float*)d_in[1];
    const float* c1b  = (const float*)d_in[2];
    const float* c2w  = (const float*)d_in[3];
    const float* c2b  = (const float*)d_in[4];
    const float* f1w  = (const float*)d_in[5];
    const float* f1b  = (const float*)d_in[6];
    const float* f2w  = (const float*)d_in[7];
    const float* f2b  = (const float*)d_in[8];
    const float* f3w  = (const float*)d_in[9];
    const float* f3b  = (const float*)d_in[10];
    const float* cen  = (const float*)d_in[11];
    const float* momw = (const float*)d_in[12];
    const float* gm1  = (const float*)d_in[13];
    const float* gm2  = (const float*)d_in[14];
    const float* gm3  = (const float*)d_in[15];

    float* ws      = (float*)d_ws;
    float* pairm   = ws + OFF_PAIR;
    float* fc1p    = ws + OFF_FC1P;
    u16*   ptfh    = (u16*)(ws + OFF_PTFH);
    u16*   ptfl    = (u16*)(ws + OFF_PTFL);
    float* pooled  = ws + OFF_POOL;
    float* dov     = ws + OFF_DO;
    float* cwp     = ws + OFF_CW;
    int*   iws     = (int*)(ws + OFF_INT);
    int*   cls_cnt = iws;
    int*   cls_idx = iws + 16;
    float* wT      = ws + OFF_WT;
    float* out     = (float*)d_out;

    k_conv12<<<2592, 256, 0, stream>>>(x, c1w, c1b, c2w, c2b, pooled,
                                       f1w, wT, cwp, cls_cnt, out);
    k_fc1<<<1024, 256, 0, stream>>>(pooled, wT, fc1p);
    k_fc23a<<<256, 128, 0, stream>>>(fc1p, f1b, f2w, f2b, f3w, f3b, cen, out,
                                     dov, pairm, cwp, cls_cnt, cls_idx);
    k_prep<<<1098, 256, 0, stream>>>(pairm, dov, cwp, cls_cnt, cls_idx, momw,
                                     gm1, gm2, gm3, ptfh, ptfl, out);
    k_p4<<<1710, 256, 0, stream>>>(ptfh, ptfl, cwp, cls_cnt, momw, out);
}

// Round 16
// 252.256 us; speedup vs baseline: 1.0834x; 1.0834x over previous
//
#include <hip/hip_runtime.h>
#include <math.h>

// ---------------- problem constants ----------------
#define BATCH   256
#define NCLS    10
#define DIM     48

// ---------------- workspace layout (float elements) ----------------
// h1b (u16 view) occupies [0, 7372800) FLOATS — live conv1->conv2 only.
// ptf* alias dead-h1b (written by k_prep, long after conv2). wT now DISJOINT.
#define OFF_H1B   0            // 256*900*64 u16 = 7,372,800 floats
#define OFF_PAIR  0            // 589824 (after conv2)
#define OFF_FC1P  602112       // ends 2699264
#define OFF_PTFH  4500000      // 144*18*64*8 u16 = 663552 fl -> ends 5163552
#define OFF_PTFL  5300000      // ends 5963552
#define OFF_POOL  7372800      // ends 10584064
#define OFF_DO    10596352
#define OFF_CW    10608640
#define OFF_INT   10608656     // ints: cls_cnt[16], cls_idx[2560] -> ends 10611232
#define OFF_WPH   10612000     // 18432 u16 -> ends 10621216
#define OFF_WPL   10622000     // ends 10631216
#define OFF_WT    11000000     // 12544*128 -> ends 12605632 (DISJOINT)

typedef __attribute__((ext_vector_type(8))) short short8;
typedef __attribute__((ext_vector_type(4))) float floatx4;
typedef unsigned short u16;
typedef unsigned int u32;

__device__ __forceinline__ u16 f2bf(float v) {
    u32 u = __float_as_uint(v);
    return (u16)((u + 0x7fffu + ((u >> 16) & 1u)) >> 16);
}
__device__ __forceinline__ float bf2f(u16 h) {
    return __uint_as_float(((u32)h) << 16);
}

__device__ __forceinline__ float sroot_half(float m) {
    float s = (m < 0.f) ? -1.f : 1.f;
    return s * (sqrtf(fabsf(m) + 0.25f) - 0.5f);
}
__device__ __forceinline__ float sroot_cbrt(float m) {
    float s = (m < 0.f) ? -1.f : 1.f;
    return s * (cbrtf(fabsf(m) + 0.19245008973f) - 0.57735026919f);
}
__device__ __forceinline__ float sroot_quarter(float m) {
    float s = (m < 0.f) ? -1.f : 1.f;
    return s * (sqrtf(sqrtf(fabsf(m) + 0.15749013123f)) - 0.62996052494f);
}

// ------- conv1 (1 pos/thread, all 32 oc) + init + wprep + folded fc1-W transpose -------
// blocks [0,900): conv1. block 900: wprep. blocks [901,2469): wtrans 32x32 tiles.
__global__ void k_conv1(const float* __restrict__ x, const float* __restrict__ w,
                        const float* __restrict__ bias, u16* __restrict__ h1b,
                        const float* __restrict__ c2w, u16* __restrict__ wph,
                        u16* __restrict__ wpl, const float* __restrict__ f1w,
                        float* __restrict__ wT, float* __restrict__ cw,
                        int* __restrict__ cls_cnt, float* __restrict__ out) {
    __shared__ float tile[32][33];
    int blk = blockIdx.x;
    int tid = threadIdx.x;
    if (blk > 900) {
        // ---- fc1-W transpose: wT[k][n] = f1w[n][k] ----
        int wb = blk - 901;                // 0..1567
        int kb = wb % 392, nb = wb / 392;
        int tx = tid & 31, ty = tid >> 5;
        int k0 = kb * 32, n0 = nb * 32;
#pragma unroll
        for (int r = 0; r < 4; r++)
            tile[tx][ty * 4 + r] = f1w[(n0 + ty * 4 + r) * 12544 + k0 + tx];
        __syncthreads();
#pragma unroll
        for (int r = 0; r < 4; r++)
            wT[(k0 + ty * 4 + r) * 128 + n0 + tx] = tile[ty * 4 + r][tx];
        return;
    }
    if (blk == 900) {
        // wprep layout: [s(9)][icq(4)][oc(64)][icr(8)]  (B-fragment register order)
        for (int i = tid; i < 18432; i += 256) {
            int icr = i & 7, rest = i >> 3;
            int oc = rest & 63, rest2 = rest >> 6;
            int icq = rest2 & 3, s = rest2 >> 2;
            int ic = icq * 8 + icr;
            float v = c2w[(oc * 32 + ic) * 9 + s];
            u16 hi = f2bf(v);
            wph[i] = hi;
            wpl[i] = f2bf(v - bf2f(hi));
        }
        return;
    }
    if (blk == 0) {
        if (tid < 16) { cw[tid] = 0.f; cls_cnt[tid] = 0; }
        else if (tid < 20) out[2560 + tid - 16] = 0.f;
    }
    int pos = blk * 256 + tid;             // [0, 230400)
    int b = pos / 900, rem = pos % 900;
    int y = rem / 30, xx = rem % 30;
    float win[27];
#pragma unroll
    for (int ic = 0; ic < 3; ic++)
#pragma unroll
        for (int ky = 0; ky < 3; ky++)
#pragma unroll
            for (int kx = 0; kx < 3; kx++)
                win[ic * 9 + ky * 3 + kx] = x[b * 3072 + ic * 1024 + (y + ky) * 32 + xx + kx];
    u16* hp = h1b + (size_t)pos * 64;
#pragma unroll
    for (int ch = 0; ch < 4; ch++) {
        u32 hiw[4], low[4];
#pragma unroll
        for (int a2 = 0; a2 < 4; a2++) {
            u16 h2[2], l2[2];
#pragma unroll
            for (int e = 0; e < 2; e++) {
                int oc = ch * 8 + a2 * 2 + e;
                float s = bias[oc];
#pragma unroll
                for (int k = 0; k < 27; k++) s = fmaf(win[k], w[oc * 27 + k], s);
                s = fmaxf(s, 0.f);
                u16 hi = f2bf(s);
                h2[e] = hi;
                l2[e] = f2bf(s - bf2f(hi));
            }
            hiw[a2] = (u32)h2[0] | ((u32)h2[1] << 16);
            low[a2] = (u32)l2[0] | ((u32)l2[1] << 16);
        }
        *(uint4*)(hp + ch * 8)      = make_uint4(hiw[0], hiw[1], hiw[2], hiw[3]);
        *(uint4*)(hp + 32 + ch * 8) = make_uint4(low[0], low[1], low[2], low[3]);
    }
}

// -------- conv2 + relu + 2x2 maxpool via MFMA bf16x2 (3-term) --------
__global__ void k_conv2(const u16* __restrict__ h1b, const u16* __restrict__ wph,
                        const u16* __restrict__ wpl, const float* __restrict__ bias,
                        float* __restrict__ pooled) {
    __shared__ u16 hs[256 * 72];
    int blk = blockIdx.x;
    int b = blk >> 2, sub = blk & 3;
    int hy = sub >> 1, hx = sub & 1;
    int row0 = hy * 14, col0 = hx * 14;
    int tid = threadIdx.x;
    for (int i = tid; i < 2048; i += 256) {
        int p = i >> 3, c8 = i & 7;
        int r = p >> 4, cc = p & 15;
        size_t gp = (size_t)b * 900 + (size_t)(row0 + r) * 30 + col0 + cc;
        *(uint4*)(&hs[p * 72 + c8 * 8]) = *(const uint4*)(&h1b[gp * 64 + c8 * 8]);
    }
    int wv = tid >> 6, lane = tid & 63;
    int n = lane & 15, quad = lane >> 4;
    int ocb = wv * 16 + n;
    float bv = bias[ocb];
    short8 bh[9], bl[9];
#pragma unroll
    for (int s = 0; s < 9; s++) {
        int off = (((s * 4 + quad) * 64) + ocb) * 8;
        bh[s] = *(const short8*)(&wph[off]);
        bl[s] = *(const short8*)(&wpl[off]);
    }
    __syncthreads();
    int ml = lane & 15;
    for (int t = 0; t < 13; t++) {
        int gA = t * 4 + (ml >> 2);
        int d = ml & 3;
        int gc = (gA < 49) ? gA : 0;
        int py = gc / 7, px = gc % 7;
        int rb = 2 * py + (d >> 1), cb = 2 * px + (d & 1);
        floatx4 acc = {0.f, 0.f, 0.f, 0.f};
#pragma unroll
        for (int s = 0; s < 9; s++) {
            int ky = s / 3, kx = s % 3;
            int pos = (rb + ky) * 16 + cb + kx;
            short8 ah = *(const short8*)(&hs[pos * 72 + quad * 8]);
            short8 al = *(const short8*)(&hs[pos * 72 + 32 + quad * 8]);
            acc = __builtin_amdgcn_mfma_f32_16x16x32_bf16(ah, bh[s], acc, 0, 0, 0);
            acc = __builtin_amdgcn_mfma_f32_16x16x32_bf16(ah, bl[s], acc, 0, 0, 0);
            acc = __builtin_amdgcn_mfma_f32_16x16x32_bf16(al, bh[s], acc, 0, 0, 0);
        }
        int G = t * 4 + quad;
        if (G < 49) {
            float v = fmaxf(fmaxf(acc.x, acc.y), fmaxf(acc.z, acc.w));
            v = fmaxf(v + bv, 0.f);
            int pyg = hy * 7 + G / 7, pxg = hx * 7 + G % 7;
            pooled[(size_t)b * 12544 + ocb * 196 + pyg * 14 + pxg] = v;
        }
    }
}

// ---------------- fc1 K-split GEMM ----------------
__global__ void k_fc1(const float* __restrict__ pooled, const float* __restrict__ wT,
                      float* __restrict__ fc1p) {
    __shared__ __align__(16) float Alds[16 * 196];
    int blk = blockIdx.x;
    int sg = blk >> 6, kc = blk & 63;
    int tid = threadIdx.x;
    int m0 = sg * 16, k0 = kc * 196;
    for (int i = tid; i < 784; i += 256) {
        int m = i / 49, u = i % 49;
        ((float4*)Alds)[m * 49 + u] = ((const float4*)(pooled + (m0 + m) * 12544 + k0))[u];
    }
    __syncthreads();
    int n2 = tid & 63, mg = tid >> 6;
    const float* wp = wT + (size_t)k0 * 128 + n2;
    const float* arow = Alds + mg * 4 * 196;
    float acc[4][2];
#pragma unroll
    for (int j = 0; j < 4; j++) { acc[j][0] = 0.f; acc[j][1] = 0.f; }
    for (int k = 0; k < 196; k += 2) {
        float wa0 = wp[k * 128],        wb0 = wp[k * 128 + 64];
        float wa1 = wp[(k + 1) * 128],  wb1 = wp[(k + 1) * 128 + 64];
#pragma unroll
        for (int j = 0; j < 4; j++) {
            float2 av = *(const float2*)(arow + j * 196 + k);
            acc[j][0] = fmaf(av.x, wa0, acc[j][0]);
            acc[j][0] = fmaf(av.y, wa1, acc[j][0]);
            acc[j][1] = fmaf(av.x, wb0, acc[j][1]);
            acc[j][1] = fmaf(av.y, wb1, acc[j][1]);
        }
    }
#pragma unroll
    for (int j = 0; j < 4; j++) {
        int m = m0 + mg * 4 + j;
        fc1p[kc * 32768 + m * 128 + n2]      = acc[j][0];
        fc1p[kc * 32768 + m * 128 + n2 + 64] = acc[j][1];
    }
}

// ------- fc1-reduce + fc2 + fc3 + assignment + pair row -------
__global__ void k_fc23a(const float* __restrict__ fc1p, const float* __restrict__ f1b,
                        const float* __restrict__ w2, const float* __restrict__ b2,
                        const float* __restrict__ w3, const float* __restrict__ b3,
                        const float* __restrict__ centers, float* __restrict__ out,
                        float* __restrict__ dov, float* __restrict__ pairm,
                        float* __restrict__ cw, int* __restrict__ cls_cnt,
                        int* __restrict__ cls_idx) {
    __shared__ float a[128], h[128], zb[48], dvs[48];
    __shared__ float dist[10];
    __shared__ float smn, ssum;
    __shared__ int sarg;
    int b = blockIdx.x, t = threadIdx.x;
    float s0 = f1b[t];
    for (int p = 0; p < 64; p++) s0 += fc1p[p * 32768 + b * 128 + t];
    a[t] = fmaxf(s0, 0.f);
    __syncthreads();
    float s = b2[t];
    const float* wr = w2 + t * 128;
#pragma unroll 4
    for (int k = 0; k < 128; k++) s = fmaf(wr[k], a[k], s);
    h[t] = fmaxf(s, 0.f);
    __syncthreads();
    if (t < 48) {
        float s3 = b3[t];
        const float* wr3 = w3 + t * 128;
#pragma unroll 4
        for (int k = 0; k < 128; k++) s3 = fmaf(wr3[k], h[k], s3);
        zb[t] = s3;
    }
    __syncthreads();
    if (t < 10) {
        float d = 0.f;
        const float* cc = centers + t * 48;
        for (int k = 0; k < 48; k++) { float df = zb[k] - cc[k]; d = fmaf(df, df, d); }
        dist[t] = d;
    }
    __syncthreads();
    if (t == 0) {
        float mn = dist[0]; int arg = 0;
        for (int c = 1; c < 10; c++) if (dist[c] < mn) { mn = dist[c]; arg = c; }
        float sum = 0.f;
        for (int c = 0; c < 10; c++) sum += expf(-0.5f * (dist[c] - mn));
        smn = mn; ssum = sum; sarg = arg;
        atomicAdd(&cw[arg], 1.f);
        int pos = atomicAdd(&cls_cnt[arg], 1);
        cls_idx[arg * 256 + pos] = b;
    }
    __syncthreads();
    if (t < 10) {
        float es = -0.5f * (dist[t] - smn);
        float resp = expf(es) / ssum;
        out[b * 10 + t] = logf(fmaxf(resp, 1e-8f));
    }
    if (t < 48) {
        float v = zb[t] - centers[sarg * 48 + t];
        dvs[t] = v;
        dov[b * 48 + t] = v;
    }
    __syncthreads();
#pragma unroll
    for (int e = 0; e < 18; e++) {
        int cell = t + 128 * e;
        pairm[b * 2304 + cell] = dvs[cell / 48] * dvs[cell % 48];
    }
}

// ------- prep: ptrans->fragment order (648) + p3 (360) + m12 split (90) -------
__global__ void k_prep(const float* __restrict__ pairm, const float* __restrict__ dov,
                       const float* __restrict__ cw, const int* __restrict__ cls_cnt,
                       const int* __restrict__ cls_idx, const float* __restrict__ momw,
                       const float* __restrict__ gm1, const float* __restrict__ gm2,
                       const float* __restrict__ gm3, u16* __restrict__ ptfh,
                       u16* __restrict__ ptfl, float* __restrict__ out) {
    __shared__ __align__(16) float smem[7424];       // 29.7 KB
    int blk = blockIdx.x;
    int t = threadIdx.x;

    if (blk < 648) {
        float* tile = smem;               // 32 cols x 64 cells, stride 65
        int* cmap = (int*)(smem + 2080);
        int ctile = blk / 18, coltile = blk % 18;
        int cell0 = ctile * 64, col0 = coltile * 32;
        if (t < 32) {
            int j = col0 + t, base = 0, samp = -1;
            for (int c = 0; c < 10; c++) {
                int cnt = cls_cnt[c];
                if (j >= base && j < base + cnt) samp = cls_idx[c * 256 + (j - base)];
                base += (cnt + 31) & ~31;
            }
            cmap[t] = samp;
        }
        __syncthreads();
        for (int i = t; i < 2048; i += 256) {
            int u = i >> 6, ce = i & 63;
            int s = cmap[u];
            tile[u * 65 + ce] = (s >= 0) ? pairm[(size_t)s * 2304 + cell0 + ce] : 0.f;
        }
        __syncthreads();
        int kc = col0 >> 5;
        int rt0 = cell0 >> 4;
        for (int o = t; o < 2048; o += 256) {
            int rtl = o >> 9, lane = (o >> 3) & 63, j = o & 7;
            int m = lane & 15, quad = lane >> 4;
            float v = tile[(quad * 8 + j) * 65 + rtl * 16 + m];
            u16 hi = f2bf(v);
            size_t off = ((size_t)((rt0 + rtl) * 18 + kc) * 64 + lane) * 8 + j;
            ptfh[off] = hi;
            ptfl[off] = f2bf(v - bf2f(hi));
        }

    } else if (blk < 1008) {
        // ---- p3 ----
        float* Pl = smem;
        float* Dl = smem + 4096;
        float* red = smem + 7168;
        int bb = blk - 648;
        int c = bb / 36, pt = bb % 36;
        int cnt = cls_cnt[c];
        const int* cidx = cls_idx + c * 256;
        int pl = t >> 2, kq = t & 3;
        float acc[12];
#pragma unroll
        for (int m = 0; m < 12; m++) acc[m] = 0.f;
        for (int s0 = 0; s0 < cnt; s0 += 64) {
            int sc = min(64, cnt - s0);
            __syncthreads();
            for (int i = t; i < sc * 16; i += 256) {
                int row = i >> 4, u = i & 15;
                ((float4*)Pl)[row * 16 + u] =
                    ((const float4*)(pairm + (size_t)cidx[s0 + row] * 2304 + pt * 64))[u];
            }
            for (int i = t; i < sc * 12; i += 256) {
                int row = i / 12, u = i % 12;
                ((float4*)Dl)[row * 12 + u] =
                    ((const float4*)(dov + (size_t)cidx[s0 + row] * 48))[u];
            }
            __syncthreads();
            for (int s = 0; s < sc; s++) {
                float pa = Pl[s * 64 + pl];
                float4 d0 = *(const float4*)&Dl[s * 48 + kq * 12];
                float4 d1 = *(const float4*)&Dl[s * 48 + kq * 12 + 4];
                float4 d2 = *(const float4*)&Dl[s * 48 + kq * 12 + 8];
                acc[0]  = fmaf(pa, d0.x, acc[0]);  acc[1]  = fmaf(pa, d0.y, acc[1]);
                acc[2]  = fmaf(pa, d0.z, acc[2]);  acc[3]  = fmaf(pa, d0.w, acc[3]);
                acc[4]  = fmaf(pa, d1.x, acc[4]);  acc[5]  = fmaf(pa, d1.y, acc[5]);
                acc[6]  = fmaf(pa, d1.z, acc[6]);  acc[7]  = fmaf(pa, d1.w, acc[7]);
                acc[8]  = fmaf(pa, d2.x, acc[8]);  acc[9]  = fmaf(pa, d2.y, acc[9]);
                acc[10] = fmaf(pa, d2.z, acc[10]); acc[11] = fmaf(pa, d2.w, acc[11]);
            }
        }
        float cwn = cw[c] * (1.f / 256.f);
        int p = pt * 64 + pl;
        float p3c = 0.f;
#pragma unroll
        for (int m = 0; m < 12; m++) {
            int k = kq * 12 + m;
            float d3 = sroot_cbrt(acc[m]) - sroot_cbrt(gm3[p * 48 + k]);
            p3c += momw[k] * d3 * d3;
        }
        p3c *= cwn;
        red[t] = p3c; __syncthreads();
        for (int off = 128; off > 0; off >>= 1) { if (t < off) red[t] += red[t + off]; __syncthreads(); }
        if (t == 0) atomicAdd(&out[2562], red[0]);

    } else {
        // ---- m1/m2 split by r: 10 classes x 9 r-slices ----
        float* ds = smem;
        float* red = smem + 3072;
        int bb = blk - 1008;
        int c = bb / 9, r = bb % 9;
        int cnt = cls_cnt[c];
        const int* cidx = cls_idx + c * 256;
        int cell = t + 256 * r;
        int ci = cell / 48, cj = cell % 48;
        float a0 = 0.f, a1 = 0.f, a2 = 0.f, a3 = 0.f;
        float m1a = 0.f, m1b = 0.f;
        for (int s0 = 0; s0 < cnt; s0 += 64) {
            int sc = min(64, cnt - s0);
            __syncthreads();
            for (int i = t; i < sc * 48; i += 256)
                ds[i] = dov[(size_t)cidx[s0 + i / 48] * 48 + (i % 48)];
            __syncthreads();
            int s = 0;
            for (; s + 4 <= sc; s += 4) {
                a0 = fmaf(ds[s * 48 + ci],       ds[s * 48 + cj],       a0);
                a1 = fmaf(ds[(s + 1) * 48 + ci], ds[(s + 1) * 48 + cj], a1);
                a2 = fmaf(ds[(s + 2) * 48 + ci], ds[(s + 2) * 48 + cj], a2);
                a3 = fmaf(ds[(s + 3) * 48 + ci], ds[(s + 3) * 48 + cj], a3);
            }
            for (; s < sc; s++) a0 = fmaf(ds[s * 48 + ci], ds[s * 48 + cj], a0);
            if (r == 0 && t < 48) {
                int ss = 0;
                for (; ss + 2 <= sc; ss += 2) {
                    m1a += ds[ss * 48 + t];
                    m1b += ds[(ss + 1) * 48 + t];
                }
                for (; ss < sc; ss++) m1a += ds[ss * 48 + t];
            }
        }
        float denom = cw[c] + 1e-7f;
        float cwn = cw[c] * (1.f / 256.f);
        float m2v = (a0 + a1 + a2 + a3) / denom;
        float d2 = sroot_half(m2v) - sroot_half(gm2[cell]);
        float p2c = cwn * momw[cj] * d2 * d2;
        __syncthreads();
        red[t] = p2c; __syncthreads();
        for (int off = 128; off > 0; off >>= 1) { if (t < off) red[t] += red[t + off]; __syncthreads(); }
        if (t == 0) atomicAdd(&out[2561], red[0]);
        if (r == 0 && t < 48) {
            float m1v = (m1a + m1b) / denom;
            float d1 = m1v - gm1[t];
            atomicAdd(&out[2560], cwn * momw[t] * d1 * d1);
        }
    }
}

// ---- p4: M4 = P^T P per class via MFMA on fragment-ordered ptf ----
__global__ __launch_bounds__(256, 4)
void k_p4(const u16* __restrict__ ptfh, const u16* __restrict__ ptfl,
          const float* __restrict__ cw, const int* __restrict__ cls_cnt,
          const float* __restrict__ momw, float* __restrict__ out) {
    __shared__ float red[256];
    int blk = blockIdx.x;
    int c = blk / 171;
    int cnt = cls_cnt[c];
    if (cnt == 0) return;
    int rem = blk % 171;
    int pt = 0;
    while (rem >= 18 - pt) { rem -= 18 - pt; pt++; }
    int qt = pt + rem;
    int kc0 = 0;
    for (int cc = 0; cc < c; cc++) kc0 += (cls_cnt[cc] + 31) >> 5;
    int kch = (cnt + 31) >> 5;
    int t = threadIdx.x;
    int w = t >> 6, lane = t & 63;
    int ml = lane & 15, quad = lane >> 4;
    floatx4 acc[16];
#pragma unroll
    for (int i = 0; i < 16; i++) acc[i] = (floatx4){0.f, 0.f, 0.f, 0.f};
    for (int kc = 0; kc < kch; kc++) {
        short8 ah[2], al[2];
#pragma unroll
        for (int ms = 0; ms < 2; ms++) {
            int art = pt * 8 + w * 2 + ms;
            size_t aoff = ((size_t)(art * 18 + kc0 + kc) * 64 + lane) * 8;
            ah[ms] = *(const short8*)(ptfh + aoff);
            al[ms] = *(const short8*)(ptfl + aoff);
        }
#pragma unroll
        for (int ns = 0; ns < 8; ns++) {
            int brt = qt * 8 + ns;
            size_t boff = ((size_t)(brt * 18 + kc0 + kc) * 64 + lane) * 8;
            short8 bhv = *(const short8*)(ptfh + boff);
            short8 blv = *(const short8*)(ptfl + boff);
#pragma unroll
            for (int ms = 0; ms < 2; ms++) {
                int id = ms * 8 + ns;
                acc[id] = __builtin_amdgcn_mfma_f32_16x16x32_bf16(ah[ms], bhv, acc[id], 0, 0, 0);
                acc[id] = __builtin_amdgcn_mfma_f32_16x16x32_bf16(ah[ms], blv, acc[id], 0, 0, 0);
                acc[id] = __builtin_amdgcn_mfma_f32_16x16x32_bf16(al[ms], bhv, acc[id], 0, 0, 0);
            }
        }
    }
    float T1 = sroot_quarter(1.f), T3 = sroot_quarter(3.f);
    float cwn = cw[c] * (1.f / 256.f);
    bool diag = (pt == qt);
    int ipv[8], jpv[8];
    float mwpv[8];
#pragma unroll
    for (int ms = 0; ms < 2; ms++)
#pragma unroll
        for (int reg = 0; reg < 4; reg++) {
            int p = (pt * 8 + w * 2 + ms) * 16 + quad * 4 + reg;
            ipv[ms * 4 + reg] = p / 48;
            jpv[ms * 4 + reg] = p % 48;
            mwpv[ms * 4 + reg] = momw[p % 48];
        }
    float p4c = 0.f;
#pragma unroll
    for (int ns = 0; ns < 8; ns++) {
        int q = (qt * 8 + ns) * 16 + ml;
        int kq = q / 48, lq = q % 48;
        float mq = momw[lq];
#pragma unroll
        for (int ms = 0; ms < 2; ms++) {
            int id = ms * 8 + ns;
#pragma unroll
            for (int reg = 0; reg < 4; reg++) {
                int ip = ipv[ms * 4 + reg], jp = jpv[ms * 4 + reg];
                int g = ((ip == jp) && (kq == lq))
                      + ((ip == kq) && (jp == lq))
                      + ((ip == lq) && (jp == kq));
                float t4v = (g == 0) ? 0.f : ((g == 1) ? T1 : T3);
                float d4 = sroot_quarter(acc[id][reg]) - t4v;
                float wgt = diag ? mq : (mq + mwpv[ms * 4 + reg]);
                p4c += wgt * d4 * d4;
            }
        }
    }
    p4c *= cwn;
    red[t] = p4c; __syncthreads();
    for (int off = 128; off > 0; off >>= 1) { if (t < off) red[t] += red[t + off]; __syncthreads(); }
    if (t == 0) atomicAdd(&out[2563], red[0]);
}

// ---------------- launch ----------------
extern "C" void kernel_launch(void* const* d_in, const int* in_sizes, int n_in,
                              void* d_out, int out_size, void* d_ws, size_t ws_size,
                              hipStream_t stream) {
    const float* x    = (const float*)d_in[0];
    const float* c1w  = (const float*)d_in[1];
    const float* c1b  = (const float*)d_in[2];
    const float* c2w  = (const float*)d_in[3];
    const float* c2b  = (const float*)d_in[4];
    const float* f1w  = (const float*)d_in[5];
    const float* f1b  = (const float*)d_in[6];
    const float* f2w  = (const float*)d_in[7];
    const float* f2b  = (const float*)d_in[8];
    const float* f3w  = (const float*)d_in[9];
    const float* f3b  = (const float*)d_in[10];
    const float* cen  = (const float*)d_in[11];
    const float* momw = (const float*)d_in[12];
    const float* gm1  = (const float*)d_in[13];
    const float* gm2  = (const float*)d_in[14];
    const float* gm3  = (const float*)d_in[15];

    float* ws      = (float*)d_ws;
    u16*   h1b     = (u16*)(ws + OFF_H1B);
    float* pairm   = ws + OFF_PAIR;
    float* fc1p    = ws + OFF_FC1P;
    u16*   ptfh    = (u16*)(ws + OFF_PTFH);
    u16*   ptfl    = (u16*)(ws + OFF_PTFL);
    float* pooled  = ws + OFF_POOL;
    float* dov     = ws + OFF_DO;
    float* cwp     = ws + OFF_CW;
    int*   iws     = (int*)(ws + OFF_INT);
    int*   cls_cnt = iws;
    int*   cls_idx = iws + 16;
    u16*   wph     = (u16*)(ws + OFF_WPH);
    u16*   wpl     = (u16*)(ws + OFF_WPL);
    float* wT      = ws + OFF_WT;
    float* out     = (float*)d_out;

    k_conv1<<<2469, 256, 0, stream>>>(x, c1w, c1b, h1b, c2w, wph, wpl,
                                      f1w, wT, cwp, cls_cnt, out);
    k_conv2<<<1024, 256, 0, stream>>>(h1b, wph, wpl, c2b, pooled);
    k_fc1<<<1024, 256, 0, stream>>>(pooled, wT, fc1p);
    k_fc23a<<<256, 128, 0, stream>>>(fc1p, f1b, f2w, f2b, f3w, f3b, cen, out,
                                     dov, pairm, cwp, cls_cnt, cls_idx);
    k_prep<<<1098, 256, 0, stream>>>(pairm, dov, cwp, cls_cnt, cls_idx, momw,
                                     gm1, gm2, gm3, ptfh, ptfl, out);
    k_p4<<<1710, 256, 0, stream>>>(ptfh, ptfl, cwp, cls_cnt, momw, out);
}